// Round 4
// baseline (1700.644 us; speedup 1.0000x reference)
//
#include <hip/hip_runtime.h>
#include <math.h>
#include <float.h>

#define VOCABSZ 50000
#define EMBSZ 128
#define HIDSZ 128
#define BSZ 16
#define TENCSZ 64
#define STEPSN 24
#define STARTTOK 2

#define RPBK 128          // vocab rows per step-block
#define NBLK2 391         // ceil(50000/128)
#define NSLOT 782         // partial slots (64-row granules)
#define KT 32             // K-tile columns
#define PITCH 36          // KT + 4 pad (floats)

// ws float layout
#define FEAT_OFF 0
#define HBUF_OFF (STEPSN*BSZ*256)
#define CBUF_OFF (HBUF_OFF + BSZ*HIDSZ)
#define PMAX_OFF (CBUF_OFF + STEPSN*BSZ)
#define PSUM_OFF (PMAX_OFF + NSLOT*BSZ)
#define WS_FLOATS (PSUM_OFF + NSLOT*BSZ)
// ws int layout (after floats): pidx[NSLOT*BSZ], layout [b][slot]

// ---------------------------------------------------------------------------
// Step kernel v4: LDS-staged coalesced GEMM slice.
// Block: 128 vocab rows, 4 waves = {rowhalf 0/1} x {batchhalf 0/1}.
// Each thread: 1 vocab row x 8 batches. W tile 128x32 double-buffered in LDS.
// Writes logits to out[t], folds subtract of c[t-1] into out[t-1], emits
// per-64-row-slot softmax partials.
// ---------------------------------------------------------------------------
__global__ __launch_bounds__(256) void step_kernel(
    const float* __restrict__ Wl, const float* __restrict__ bl,
    const float* __restrict__ ws_c, float* __restrict__ ws_f,
    int* __restrict__ ws_i, float* __restrict__ out, int t)
{
  __shared__ float sW[2][RPBK * PITCH];
  const int tid = threadIdx.x;
  const int lane = tid & 63;
  const int wv = tid >> 6;
  const int rowhalf = wv & 1;
  const int bh0 = __builtin_amdgcn_readfirstlane((wv >> 1) * 8);  // 0 or 8
  const int v0 = blockIdx.x * RPBK;
  const int r = rowhalf * 64 + lane;
  const int v = v0 + r;
  const bool valid = v < VOCABSZ;

  const float* feat_t = ws_c + FEAT_OFF + (size_t)t * (BSZ * 256) + bh0 * 256;
  const float4* __restrict__ Wl4 = (const float4*)Wl;

  // staging map: f4lin = i*256 + tid ; row = f4lin>>3 ; c4 = f4lin&7
  int srow[4], sc4[4], gbase[4];
#pragma unroll
  for (int i = 0; i < 4; ++i) {
    int f4lin = i * 256 + tid;
    srow[i] = f4lin >> 3;
    sc4[i] = f4lin & 7;
    int vrow = v0 + srow[i];
    if (vrow >= VOCABSZ) vrow = VOCABSZ - 1;
    gbase[i] = vrow * 64 + sc4[i];      // float4 index into Wl
  }

  float acc[8];
#pragma unroll
  for (int b = 0; b < 8; ++b) acc[b] = 0.f;

  float4 stg[4];
#pragma unroll
  for (int i = 0; i < 4; ++i) stg[i] = Wl4[gbase[i]];
#pragma unroll
  for (int i = 0; i < 4; ++i)
    *(float4*)&sW[0][srow[i] * PITCH + sc4[i] * 4] = stg[i];
  __syncthreads();

  for (int kt = 0; kt < 8; ++kt) {
    if (kt < 7) {
#pragma unroll
      for (int i = 0; i < 4; ++i) stg[i] = Wl4[gbase[i] + (kt + 1) * 8];
    }
    const float* wrow = &sW[kt & 1][r * PITCH];
    const float* fp = feat_t + kt * KT;
#pragma unroll
    for (int k4 = 0; k4 < 8; ++k4) {
      float4 wvv = *(const float4*)&wrow[k4 * 4];
#pragma unroll
      for (int b = 0; b < 8; ++b) {
        float4 f = *(const float4*)(fp + b * 256 + k4 * 4);  // wave-uniform -> s_load
        acc[b] += f.x * wvv.x + f.y * wvv.y + f.z * wvv.z + f.w * wvv.w;
      }
    }
    if (kt < 7) {
#pragma unroll
      for (int i = 0; i < 4; ++i)
        *(float4*)&sW[(kt + 1) & 1][srow[i] * PITCH + sc4[i] * 4] = stg[i];
      __syncthreads();
    }
  }

  const float lb = valid ? bl[v] : 0.f;
  float lg[8];
#pragma unroll
  for (int b = 0; b < 8; ++b) lg[b] = acc[b] + lb;

  if (valid) {
#pragma unroll
    for (int b = 0; b < 8; ++b)
      out[((size_t)t * BSZ + bh0 + b) * VOCABSZ + v] = lg[b];
    if (t > 0) {
      const float* cb = ws_c + CBUF_OFF + (t - 1) * BSZ + bh0;
#pragma unroll
      for (int b = 0; b < 8; ++b) {
        size_t idx = ((size_t)(t - 1) * BSZ + bh0 + b) * VOCABSZ + v;
        out[idx] = out[idx] - cb[b];
      }
    }
  }

  float* pmax = ws_f + PMAX_OFF;
  float* psum = ws_f + PSUM_OFF;
  int* pidx = ws_i;
  const int slot = blockIdx.x * 2 + rowhalf;
#pragma unroll
  for (int b = 0; b < 8; ++b) {
    float m = valid ? lg[b] : -FLT_MAX;
    int mi = valid ? v : 0x7fffffff;
#pragma unroll
    for (int off = 32; off; off >>= 1) {
      float om = __shfl_xor(m, off);
      int oi = __shfl_xor(mi, off);
      if (om > m || (om == m && oi < mi)) { m = om; mi = oi; }
    }
    float s = valid ? expf(lg[b] - m) : 0.f;
#pragma unroll
    for (int off = 32; off; off >>= 1) s += __shfl_xor(s, off);
    if (lane == 0) {
      pmax[(bh0 + b) * NSLOT + slot] = m;
      psum[(bh0 + b) * NSLOT + slot] = s;
      pidx[(bh0 + b) * NSLOT + slot] = mi;
    }
  }
}

// ---------------------------------------------------------------------------
// rg kernel: reduce step rstep's partials -> {c, token}, then GRU+attention
// for step gstep -> feat[gstep], h.  grid = 16 blocks (one per batch).
// enc_fwd[b] staged in LDS (pitch 132) to coalesce score/attn loops.
// ---------------------------------------------------------------------------
__global__ __launch_bounds__(256) void rg_kernel(
    const float* __restrict__ enc, const float* __restrict__ inith,
    const float* __restrict__ embed,
    const float* __restrict__ W_ih, const float* __restrict__ W_hh,
    const float* __restrict__ b_ih, const float* __restrict__ b_hh,
    float* __restrict__ ws_f, int* __restrict__ ws_i,
    float* __restrict__ out, int rstep, int gstep)
{
  const int b = blockIdx.x, tid = threadIdx.x;
  float* feat = ws_f + FEAT_OFF;
  float* hbuf = ws_f + HBUF_OFF;
  float* cbuf = ws_f + CBUF_OFF;
  float* pmax = ws_f + PMAX_OFF;
  float* psum = ws_f + PSUM_OFF;
  int* pidx = ws_i;

  __shared__ float s_enc[64 * 132];
  __shared__ float s_wm[4]; __shared__ int s_wi[4];
  __shared__ float s_ws[4];
  __shared__ int s_tok;
  __shared__ float s_emb[EMBSZ];
  __shared__ float s_h[HIDSZ];
  __shared__ float s_hnew[HIDSZ];
  __shared__ float s_gh[3 * HIDSZ];
  __shared__ float s_probs[TENCSZ];

  const int lane = tid & 63, wave = tid >> 6;

  if (gstep >= 0) {
    // stage enc_fwd[b]: 64 rows x 128 floats (first half of each 256-row)
#pragma unroll
    for (int i = 0; i < 8; ++i) {
      int f4lin = i * 256 + tid;
      int row = f4lin >> 5, c = f4lin & 31;
      float4 e = ((const float4*)(enc + ((size_t)b * TENCSZ + row) * 256))[c];
      *(float4*)&s_enc[row * 132 + c * 4] = e;
    }
  }

  if (rstep >= 0) {
    float m = -FLT_MAX; int mi = 0x7fffffff;
    for (int i = tid; i < NSLOT; i += 256) {
      float mm = pmax[b * NSLOT + i]; int ii = pidx[b * NSLOT + i];
      if (mm > m || (mm == m && ii < mi)) { m = mm; mi = ii; }
    }
#pragma unroll
    for (int off = 32; off; off >>= 1) {
      float om = __shfl_xor(m, off); int oi = __shfl_xor(mi, off);
      if (om > m || (om == m && oi < mi)) { m = om; mi = oi; }
    }
    if (lane == 0) { s_wm[wave] = m; s_wi[wave] = mi; }
    __syncthreads();
    float gm = s_wm[0]; int gi_ = s_wi[0];
#pragma unroll
    for (int w = 1; w < 4; ++w) {
      if (s_wm[w] > gm || (s_wm[w] == gm && s_wi[w] < gi_)) { gm = s_wm[w]; gi_ = s_wi[w]; }
    }
    float e = 0.f;
    for (int i = tid; i < NSLOT; i += 256)
      e += psum[b * NSLOT + i] * expf(pmax[b * NSLOT + i] - gm);
#pragma unroll
    for (int off = 32; off; off >>= 1) e += __shfl_xor(e, off);
    if (lane == 0) s_ws[wave] = e;
    __syncthreads();
    if (tid == 0) {
      float tot = s_ws[0] + s_ws[1] + s_ws[2] + s_ws[3];
      cbuf[rstep * BSZ + b] = gm + logf(tot);
      out[(size_t)STEPSN * BSZ * VOCABSZ + rstep * BSZ + b] = (float)gi_;
      s_tok = gi_;
    }
    __syncthreads();
  }

  if (gstep >= 0) {
    const int tok = (gstep == 0) ? STARTTOK : s_tok;
    if (tid < 128) {
      s_emb[tid] = embed[(size_t)tok * EMBSZ + tid];
      s_h[tid] = (gstep == 0) ? inith[b * HIDSZ + tid] : hbuf[b * HIDSZ + tid];
    }
    __syncthreads();
    float gr = 0.f, gz = 0.f, gn = 0.f;
    if (tid < 128) {
      gr = b_ih[tid]; gz = b_ih[tid + 128]; gn = b_ih[tid + 256];
      const float* wr = W_ih + (size_t)tid * EMBSZ;
      const float* wz = W_ih + (size_t)(tid + 128) * EMBSZ;
      const float* wn = W_ih + (size_t)(tid + 256) * EMBSZ;
      for (int k = 0; k < EMBSZ; ++k) {
        float e = s_emb[k];
        gr += wr[k] * e; gz += wz[k] * e; gn += wn[k] * e;
      }
    } else {
      int j = tid - 128;
      float hr = b_hh[j], hz = b_hh[j + 128], hn = b_hh[j + 256];
      const float* wr = W_hh + (size_t)j * HIDSZ;
      const float* wz = W_hh + (size_t)(j + 128) * HIDSZ;
      const float* wn = W_hh + (size_t)(j + 256) * HIDSZ;
      for (int k = 0; k < HIDSZ; ++k) {
        float h = s_h[k];
        hr += wr[k] * h; hz += wz[k] * h; hn += wn[k] * h;
      }
      s_gh[j] = hr; s_gh[128 + j] = hz; s_gh[256 + j] = hn;
    }
    __syncthreads();
    if (tid < 128) {
      float r = 1.f / (1.f + expf(-(gr + s_gh[tid])));
      float z = 1.f / (1.f + expf(-(gz + s_gh[128 + tid])));
      float n = tanhf(gn + r * s_gh[256 + tid]);
      s_hnew[tid] = (1.f - z) * n + z * s_h[tid];
    }
    __syncthreads();
    if (tid < 64) {
      const float4* ep = (const float4*)&s_enc[tid * 132];
      const float4* h4 = (const float4*)s_hnew;
      float sc = 0.f;
#pragma unroll
      for (int k = 0; k < 32; ++k) {
        float4 e = ep[k], h = h4[k];
        sc += e.x * h.x + e.y * h.y + e.z * h.z + e.w * h.w;
      }
      float mx = sc;
#pragma unroll
      for (int off = 32; off; off >>= 1) mx = fmaxf(mx, __shfl_xor(mx, off));
      float p = expf(sc - mx);
      float su = p;
#pragma unroll
      for (int off = 32; off; off >>= 1) su += __shfl_xor(su, off);
      s_probs[tid] = p / su;
    }
    __syncthreads();
    if (tid < 128) {
      float a = 0.f;
#pragma unroll 8
      for (int tt = 0; tt < TENCSZ; ++tt)
        a += s_probs[tt] * s_enc[tt * 132 + tid];
      float* fptr = feat + ((size_t)gstep * BSZ + b) * 256;
      fptr[tid] = a;
      fptr[128 + tid] = s_hnew[tid];
      hbuf[b * HIDSZ + tid] = s_hnew[tid];
    }
  }
}

// ---------------------------------------------------------------------------
// Last-step subtract: out[23,b,v] -= c[23,b]. 800000 floats, 8 per thread.
// ---------------------------------------------------------------------------
__global__ __launch_bounds__(256) void sub_last_kernel(
    const float* __restrict__ cbuf, float* __restrict__ out)
{
  size_t i = ((size_t)blockIdx.x * 256 + threadIdx.x) * 8;
  if (i >= (size_t)BSZ * VOCABSZ) return;
  int b = (int)(i / VOCABSZ);           // 8 | VOCABSZ -> no row straddle
  float c = cbuf[(STEPSN - 1) * BSZ + b];
  float4* p = (float4*)(out + (size_t)(STEPSN - 1) * BSZ * VOCABSZ + i);
  float4 x0 = p[0], x1 = p[1];
  x0.x -= c; x0.y -= c; x0.z -= c; x0.w -= c;
  x1.x -= c; x1.y -= c; x1.z -= c; x1.w -= c;
  p[0] = x0; p[1] = x1;
}

extern "C" void kernel_launch(void* const* d_in, const int* in_sizes, int n_in,
                              void* d_out, int out_size, void* d_ws, size_t ws_size,
                              hipStream_t stream)
{
  const float* enc   = (const float*)d_in[0];
  const float* inith = (const float*)d_in[1];
  const float* embed = (const float*)d_in[2];
  const float* W_ih  = (const float*)d_in[3];
  const float* W_hh  = (const float*)d_in[4];
  const float* b_ih  = (const float*)d_in[5];
  const float* b_hh  = (const float*)d_in[6];
  const float* Wl    = (const float*)d_in[7];
  const float* bl    = (const float*)d_in[8];
  float* out = (float*)d_out;

  float* ws_f = (float*)d_ws;
  int* ws_i = (int*)(ws_f + WS_FLOATS);

  rg_kernel<<<BSZ, 256, 0, stream>>>(enc, inith, embed, W_ih, W_hh, b_ih, b_hh,
                                     ws_f, ws_i, out, -1, 0);
  for (int t = 0; t < STEPSN; ++t) {
    step_kernel<<<NBLK2, 256, 0, stream>>>(Wl, bl, ws_f, ws_f, ws_i, out, t);
    rg_kernel<<<BSZ, 256, 0, stream>>>(enc, inith, embed, W_ih, W_hh, b_ih, b_hh,
                                       ws_f, ws_i, out, t, (t < STEPSN - 1) ? (t + 1) : -1);
  }
  const int nsub = (BSZ * VOCABSZ / 8 + 255) / 256;
  sub_last_kernel<<<nsub, 256, 0, stream>>>(ws_f + CBUF_OFF, out);
}